// Round 1
// baseline (797.089 us; speedup 1.0000x reference)
//
#include <hip/hip_runtime.h>
#include <hip/hip_bf16.h>

typedef __attribute__((ext_vector_type(4))) float f32x4;
typedef __attribute__((ext_vector_type(8))) short bf16x8;

__device__ __forceinline__ unsigned short f2bf(float f) {
  unsigned int u = __builtin_bit_cast(unsigned int, f);
  u += 0x7fffu + ((u >> 16) & 1u);          // round-to-nearest-even
  return (unsigned short)(u >> 16);
}

__device__ __forceinline__ f32x4 mfma16(bf16x8 a, bf16x8 b, f32x4 c) {
  return __builtin_amdgcn_mfma_f32_16x16x32_bf16(a, b, c, 0, 0, 0);
}

// C[M,N] = A[M,K](fp32) * B[N,K](fp32)^T ; bf16 MFMA, fp32 accum.
// 128x128 tile, BK=32, 256 threads (4 waves in 2x2), 64x64 per wave.
// MODE 0: qh bf16 out, *0.125, layout [M,512]
// MODE 1: kv split: cols<512 -> k[B,H,4096,64] bf16 ; cols>=512 -> vT[B,H,64,4096] bf16
// MODE 2: fp32 out + bias
template<int MODE>
__global__ __launch_bounds__(256)
void gemm_bt(const float* __restrict__ A, const float* __restrict__ Bm,
             void* __restrict__ Cout, const float* __restrict__ bias, int K)
{
  __shared__ unsigned short As[128*32];
  __shared__ unsigned short Bs[128*32];
  const int t = threadIdx.x;
  const int lane = t & 63;
  const int w = t >> 6;
  const int wr = w >> 1, wc = w & 1;
  const int row0 = blockIdx.y * 128, col0 = blockIdx.x * 128;
  f32x4 acc[4][4] = {};

  for (int k0 = 0; k0 < K; k0 += 32) {
    #pragma unroll
    for (int p = 0; p < 4; ++p) {
      const int r = p*32 + (t >> 3);
      const int c = (t & 7) * 4;
      float4 va = *reinterpret_cast<const float4*>(A  + (size_t)(row0 + r)*K + k0 + c);
      float4 vb = *reinterpret_cast<const float4*>(Bm + (size_t)(col0 + r)*K + k0 + c);
      ushort4 sa, sb;
      sa.x = f2bf(va.x); sa.y = f2bf(va.y); sa.z = f2bf(va.z); sa.w = f2bf(va.w);
      sb.x = f2bf(vb.x); sb.y = f2bf(vb.y); sb.z = f2bf(vb.z); sb.w = f2bf(vb.w);
      *reinterpret_cast<ushort4*>(&As[r*32 + c]) = sa;
      *reinterpret_cast<ushort4*>(&Bs[r*32 + c]) = sb;
    }
    __syncthreads();
    bf16x8 af[4], bfr[4];
    #pragma unroll
    for (int i = 0; i < 4; ++i) {
      af[i]  = *reinterpret_cast<const bf16x8*>(&As[(wr*64 + i*16 + (lane&15))*32 + (lane>>4)*8]);
      bfr[i] = *reinterpret_cast<const bf16x8*>(&Bs[(wc*64 + i*16 + (lane&15))*32 + (lane>>4)*8]);
    }
    #pragma unroll
    for (int i = 0; i < 4; ++i)
      #pragma unroll
      for (int j = 0; j < 4; ++j)
        acc[i][j] = mfma16(af[i], bfr[j], acc[i][j]);
    __syncthreads();
  }

  #pragma unroll
  for (int i = 0; i < 4; ++i) {
    #pragma unroll
    for (int j = 0; j < 4; ++j) {
      #pragma unroll
      for (int r = 0; r < 4; ++r) {
        const int gm = row0 + wr*64 + i*16 + (lane >> 4)*4 + r;
        const int gn = col0 + wc*64 + j*16 + (lane & 15);
        const float v = acc[i][j][r];
        if constexpr (MODE == 0) {
          ((unsigned short*)Cout)[(size_t)gm*512 + gn] = f2bf(v * 0.125f);
        } else if constexpr (MODE == 1) {
          const int b = gm >> 12, nn = gm & 4095;
          if (gn < 512) {
            const int h = gn >> 6, d = gn & 63;
            ((unsigned short*)Cout)[(((size_t)(b*8 + h)*4096 + nn) << 6) + d] = f2bf(v);
          } else {
            const int c2 = gn - 512, h = c2 >> 6, d = c2 & 63;
            ((unsigned short*)Cout)[67108864ULL + ((size_t)(b*8 + h)*64 + d)*4096 + nn] = f2bf(v);
          }
        } else {
          ((float*)Cout)[(size_t)gm*512 + gn] = v + bias[gn];
        }
      }
    }
  }
}

// Flash attention: grid = B*H = 256 blocks, 256 threads (4 waves x 32 q-rows).
// qh [B*128,512] bf16; k [B*H,4096,64] bf16; vT [B*H,64,4096] bf16;
// mask [B,128,4096] fp32; xout [B*128,512] fp32.
__global__ __launch_bounds__(256)
void attn_fwd(const unsigned short* __restrict__ qh,
              const unsigned short* __restrict__ kbuf,
              const unsigned short* __restrict__ vT,
              const float* __restrict__ mask,
              float* __restrict__ xout)
{
  __shared__ unsigned short Ks[64*64];
  __shared__ unsigned short Vs[64*64];
  __shared__ unsigned short Ps[4][32*64];
  const int bh = blockIdx.x;
  const int b = bh >> 3, h = bh & 7;
  const int t = threadIdx.x, lane = t & 63, w = t >> 6;

  bf16x8 aq[2][2];
  #pragma unroll
  for (int mi = 0; mi < 2; ++mi)
    #pragma unroll
    for (int kk = 0; kk < 2; ++kk)
      aq[mi][kk] = *reinterpret_cast<const bf16x8*>(
          qh + (size_t)(b*128 + w*32 + mi*16 + (lane&15))*512 + h*64 + kk*32 + (lane>>4)*8);

  float mrow[8], lrow[8];
  #pragma unroll
  for (int i = 0; i < 8; ++i) { mrow[i] = -1e30f; lrow[i] = 0.f; }
  f32x4 o[2][4] = {};

  const unsigned short* kp = kbuf + (size_t)bh * 4096 * 64;
  const unsigned short* vp = vT   + (size_t)bh * 64 * 4096;
  const float*          mp = mask + (size_t)b * 128 * 4096;

  for (int nt = 0; nt < 64; ++nt) {
    { // stage K tile (contiguous 8 KB) and V^T tile (64 rows x 128 B)
      const uint4* src = reinterpret_cast<const uint4*>(kp + (size_t)nt * 4096);
      uint4* dst = reinterpret_cast<uint4*>(Ks);
      dst[t]       = src[t];
      dst[t + 256] = src[t + 256];
      const int d0 = t >> 3, nc = (t & 7) * 8;
      *reinterpret_cast<uint4*>(&Vs[d0*64 + nc]) =
          *reinterpret_cast<const uint4*>(vp + (size_t)d0*4096 + nt*64 + nc);
      *reinterpret_cast<uint4*>(&Vs[(d0 + 32)*64 + nc]) =
          *reinterpret_cast<const uint4*>(vp + (size_t)(d0 + 32)*4096 + nt*64 + nc);
    }
    __syncthreads();

    // S = qh * K^T  (rows q, cols n)
    f32x4 s[2][4] = {};
    #pragma unroll
    for (int ni = 0; ni < 4; ++ni) {
      #pragma unroll
      for (int kk = 0; kk < 2; ++kk) {
        bf16x8 kf = *reinterpret_cast<const bf16x8*>(
            &Ks[(ni*16 + (lane&15))*64 + kk*32 + (lane>>4)*8]);
        s[0][ni] = mfma16(aq[0][kk], kf, s[0][ni]);
        s[1][ni] = mfma16(aq[1][kk], kf, s[1][ni]);
      }
    }
    // additive mask
    #pragma unroll
    for (int mi = 0; mi < 2; ++mi)
      #pragma unroll
      for (int ni = 0; ni < 4; ++ni)
        #pragma unroll
        for (int r = 0; r < 4; ++r)
          s[mi][ni][r] += mp[(size_t)(w*32 + mi*16 + (lane>>4)*4 + r)*4096
                             + nt*64 + ni*16 + (lane&15)];

    // online softmax: rows live on (lane>>4)*4+r; 16 lanes share a row set
    #pragma unroll
    for (int mi = 0; mi < 2; ++mi) {
      #pragma unroll
      for (int r = 0; r < 4; ++r) {
        float mx = fmaxf(fmaxf(s[mi][0][r], s[mi][1][r]), fmaxf(s[mi][2][r], s[mi][3][r]));
        #pragma unroll
        for (int off = 1; off < 16; off <<= 1)
          mx = fmaxf(mx, __shfl_xor(mx, off, 64));
        const int idx = mi*4 + r;
        const float mnew = fmaxf(mrow[idx], mx);
        const float corr = __expf(mrow[idx] - mnew);
        mrow[idx] = mnew;
        float ls = 0.f;
        #pragma unroll
        for (int ni = 0; ni < 4; ++ni) {
          const float p = __expf(s[mi][ni][r] - mnew);
          s[mi][ni][r] = p;
          ls += p;
        }
        #pragma unroll
        for (int off = 1; off < 16; off <<= 1)
          ls += __shfl_xor(ls, off, 64);
        lrow[idx] = lrow[idx]*corr + ls;
        #pragma unroll
        for (int di = 0; di < 4; ++di)
          o[mi][di][r] *= corr;
      }
    }

    // P -> per-wave LDS (bf16), re-read as A-fragments
    #pragma unroll
    for (int mi = 0; mi < 2; ++mi)
      #pragma unroll
      for (int ni = 0; ni < 4; ++ni)
        #pragma unroll
        for (int r = 0; r < 4; ++r)
          Ps[w][(mi*16 + (lane>>4)*4 + r)*64 + ni*16 + (lane&15)] = f2bf(s[mi][ni][r]);

    // O += P * V   (A = P [32 x 64n], Bt = vT [64d x 64n])
    #pragma unroll
    for (int kk = 0; kk < 2; ++kk) {
      bf16x8 pa0 = *reinterpret_cast<const bf16x8*>(&Ps[w][((lane&15))*64 + kk*32 + (lane>>4)*8]);
      bf16x8 pa1 = *reinterpret_cast<const bf16x8*>(&Ps[w][(16 + (lane&15))*64 + kk*32 + (lane>>4)*8]);
      #pragma unroll
      for (int di = 0; di < 4; ++di) {
        bf16x8 vf = *reinterpret_cast<const bf16x8*>(
            &Vs[(di*16 + (lane&15))*64 + kk*32 + (lane>>4)*8]);
        o[0][di] = mfma16(pa0, vf, o[0][di]);
        o[1][di] = mfma16(pa1, vf, o[1][di]);
      }
    }
    __syncthreads();
  }

  #pragma unroll
  for (int mi = 0; mi < 2; ++mi)
    #pragma unroll
    for (int di = 0; di < 4; ++di)
      #pragma unroll
      for (int r = 0; r < 4; ++r) {
        const int qrow = w*32 + mi*16 + (lane>>4)*4 + r;
        const int d = di*16 + (lane&15);
        xout[(size_t)(b*128 + qrow)*512 + h*64 + d] = o[mi][di][r] / lrow[mi*4 + r];
      }
}

extern "C" void kernel_launch(void* const* d_in, const int* in_sizes, int n_in,
                              void* d_out, int out_size, void* d_ws, size_t ws_size,
                              hipStream_t stream) {
  const float* q     = (const float*)d_in[0];
  const float* kv    = (const float*)d_in[1];
  const float* mask  = (const float*)d_in[2];
  const float* Wq    = (const float*)d_in[3];
  const float* Wkv   = (const float*)d_in[4];
  const float* Wproj = (const float*)d_in[5];
  const float* bproj = (const float*)d_in[6];
  float* out = (float*)d_out;

  char* ws = (char*)d_ws;
  unsigned short* qhb = (unsigned short*)ws;                         // 4 MiB  : qh bf16 [4096,512]
  unsigned short* kvb = (unsigned short*)(ws + (4ULL << 20));        // 128 MiB: k bf16 [256,4096,64]
  unsigned short* vTb = kvb + 67108864ULL;                           // 128 MiB: vT bf16 [256,64,4096]
  float* x = (float*)(ws + (4ULL << 20) + (256ULL << 20));           // 8 MiB  : x fp32 [4096,512]

  // 1) qh = (q @ Wq^T) * scale            M=4096  N=512  K=512
  gemm_bt<0><<<dim3(4, 32), 256, 0, stream>>>(q, Wq, qhb, nullptr, 512);
  // 2) kvp = kv @ Wkv^T -> k, vT          M=131072 N=1024 K=512
  gemm_bt<1><<<dim3(8, 1024), 256, 0, stream>>>(kv, Wkv, kvb, nullptr, 512);
  // 3) flash attention -> x fp32
  attn_fwd<<<dim3(256), 256, 0, stream>>>(qhb, kvb, vTb, mask, x);
  // 4) out = x @ Wproj^T + bproj          M=4096  N=512  K=512
  gemm_bt<2><<<dim3(4, 32), 256, 0, stream>>>(x, Wproj, out, bproj, 512);
}

// Round 2
// 611.714 us; speedup vs baseline: 1.3030x; 1.3030x over previous
//
#include <hip/hip_runtime.h>
#include <hip/hip_bf16.h>

typedef __attribute__((ext_vector_type(4))) float f32x4;
typedef __attribute__((ext_vector_type(8))) short bf16x8;

#define GAS __attribute__((address_space(1)))
#define LAS __attribute__((address_space(3)))

__device__ __forceinline__ unsigned int cvtpk(float lo, float hi) {
  unsigned int r;
  asm("v_cvt_pk_bf16_f32 %0, %1, %2" : "=v"(r) : "v"(lo), "v"(hi));
  return r;
}
__device__ __forceinline__ unsigned short f2bf(float f) {
  return (unsigned short)cvtpk(f, f);
}
__device__ __forceinline__ f32x4 mfma16(bf16x8 a, bf16x8 b, f32x4 c) {
  return __builtin_amdgcn_mfma_f32_16x16x32_bf16(a, b, c, 0, 0, 0);
}
__device__ __forceinline__ void gl_lds16(const unsigned short* g, unsigned short* l) {
  __builtin_amdgcn_global_load_lds((const GAS unsigned short*)g, (LAS unsigned short*)l,
                                   16, 0, 0);
}

__global__ __launch_bounds__(256)
void cvt_f32_bf16(const float* __restrict__ in, unsigned short* __restrict__ out, int n8) {
  for (int i = blockIdx.x * blockDim.x + threadIdx.x; i < n8; i += gridDim.x * blockDim.x) {
    const float4 a = *reinterpret_cast<const float4*>(in + (size_t)i * 8);
    const float4 b = *reinterpret_cast<const float4*>(in + (size_t)i * 8 + 4);
    uint4 o;
    o.x = cvtpk(a.x, a.y); o.y = cvtpk(a.z, a.w);
    o.z = cvtpk(b.x, b.y); o.w = cvtpk(b.z, b.w);
    *reinterpret_cast<uint4*>(out + (size_t)i * 8) = o;
  }
}

// C[M,N] = A[M,512] * B[N,512]^T. B is bf16 (pre-converted weights).
// A fp32 (AF32=true, reg-staged + cvt_pk) or bf16 (global_load_lds).
// 128x128 tile, BK=64, 256 threads (4 waves 2x2), XOR-swizzled LDS.
// MODE 0: qh bf16 out *0.125 [M,512]; MODE 1: split k/vT bf16; MODE 2: fp32 + bias.
template<int MODE, bool AF32>
__global__ __launch_bounds__(256)
void gemm_bt(const void* __restrict__ Ap, const unsigned short* __restrict__ Bm,
             void* __restrict__ Cout, const float* __restrict__ bias)
{
  constexpr int K = 512;
  constexpr int GX = (MODE == 1) ? 8 : 4;
  __shared__ unsigned short As[128 * 64];
  __shared__ unsigned short Bs[128 * 64];
  const int t = threadIdx.x, lane = t & 63, w = t >> 6;
  const int wr = w >> 1, wc = w & 1;
  const int nwg = gridDim.x, bid = blockIdx.x;
  const int id = (bid & 7) * (nwg >> 3) + (bid >> 3);   // XCD swizzle (nwg % 8 == 0)
  const int row0 = (id / GX) * 128, col0 = (id % GX) * 128;

  f32x4 acc[4][4] = {};

  const int rB = w * 8 + (lane >> 3);      // + p*32
  const int cB = (lane & 7) * 8;
  const int rA = t >> 3;                   // + p*32
  const int cA = (t & 7) * 8;

  const float* Af = (const float*)Ap;
  const unsigned short* Ab = (const unsigned short*)Ap;

  for (int k0 = 0; k0 < K; k0 += 64) {
    #pragma unroll
    for (int p = 0; p < 4; ++p) {          // B: async global->LDS, pre-swizzled src
      const int r = p * 32 + rB;
      gl_lds16(Bm + (size_t)(col0 + r) * K + k0 + (cB ^ ((r & 7) << 3)),
               &Bs[(p * 32 + w * 8) * 64]);
    }
    if constexpr (!AF32) {
      #pragma unroll
      for (int p = 0; p < 4; ++p) {
        const int r = p * 32 + rB;
        gl_lds16(Ab + (size_t)(row0 + r) * K + k0 + (cB ^ ((r & 7) << 3)),
                 &As[(p * 32 + w * 8) * 64]);
      }
    } else {
      #pragma unroll
      for (int p = 0; p < 4; ++p) {        // A: fp32 -> cvt_pk -> swizzled ds_write
        const int r = p * 32 + rA;
        const float* src = Af + (size_t)(row0 + r) * K + k0 + cA;
        const float4 a = *reinterpret_cast<const float4*>(src);
        const float4 b = *reinterpret_cast<const float4*>(src + 4);
        uint4 o;
        o.x = cvtpk(a.x, a.y); o.y = cvtpk(a.z, a.w);
        o.z = cvtpk(b.x, b.y); o.w = cvtpk(b.z, b.w);
        *reinterpret_cast<uint4*>(&As[r * 64 + (cA ^ ((r & 7) << 3))]) = o;
      }
    }
    __syncthreads();

    bf16x8 af[2][4], bfr[2][4];
    #pragma unroll
    for (int kk = 0; kk < 2; ++kk) {
      #pragma unroll
      for (int i = 0; i < 4; ++i) {
        const int ra = wr * 64 + i * 16 + (lane & 15);
        const int rb = wc * 64 + i * 16 + (lane & 15);
        const int cc = (kk * 32 + (lane >> 4) * 8) ^ ((lane & 7) << 3);
        af[kk][i]  = *reinterpret_cast<const bf16x8*>(&As[ra * 64 + cc]);
        bfr[kk][i] = *reinterpret_cast<const bf16x8*>(&Bs[rb * 64 + cc]);
      }
    }
    #pragma unroll
    for (int kk = 0; kk < 2; ++kk)
      #pragma unroll
      for (int i = 0; i < 4; ++i)
        #pragma unroll
        for (int j = 0; j < 4; ++j)
          acc[i][j] = mfma16(af[kk][i], bfr[kk][j], acc[i][j]);
    __syncthreads();
  }

  #pragma unroll
  for (int i = 0; i < 4; ++i) {
    #pragma unroll
    for (int j = 0; j < 4; ++j) {
      #pragma unroll
      for (int r = 0; r < 4; ++r) {
        const int gm = row0 + wr * 64 + i * 16 + (lane >> 4) * 4 + r;
        const int gn = col0 + wc * 64 + j * 16 + (lane & 15);
        const float v = acc[i][j][r];
        if constexpr (MODE == 0) {
          ((unsigned short*)Cout)[(size_t)gm * 512 + gn] = f2bf(v * 0.125f);
        } else if constexpr (MODE == 1) {
          const int b = gm >> 12, nn = gm & 4095;
          if (gn < 512) {
            const int h = gn >> 6, d = gn & 63;
            ((unsigned short*)Cout)[(((size_t)(b * 8 + h) * 4096 + nn) << 6) + d] = f2bf(v);
          } else {
            const int c2 = gn - 512, h = c2 >> 6, d = c2 & 63;
            ((unsigned short*)Cout)[67108864ULL + ((size_t)(b * 8 + h) * 64 + d) * 4096 + nn] = f2bf(v);
          }
        } else {
          ((float*)Cout)[(size_t)gm * 512 + gn] = v + bias[gn];
        }
      }
    }
  }
}

// Flash attention: grid = B*H*2 = 512 blocks, 256 threads (4 waves x 16 q-rows).
// All LDS tiles XOR-swizzled (col8 ^= row&7). x out is bf16.
__global__ __launch_bounds__(256)
void attn_fwd(const unsigned short* __restrict__ qh,
              const unsigned short* __restrict__ kbuf,
              const unsigned short* __restrict__ vT,
              const float* __restrict__ mask,
              unsigned short* __restrict__ xout)
{
  __shared__ unsigned short Ks[64 * 64];
  __shared__ unsigned short Vs[64 * 64];
  __shared__ unsigned short Ps[4][16 * 64];
  const int bh2 = blockIdx.x;
  const int bh = bh2 >> 1, qhalf = bh2 & 1;
  const int b = bh >> 3, h = bh & 7;
  const int t = threadIdx.x, lane = t & 63, w = t >> 6;
  const int hi = lane >> 4, lo = lane & 15;
  const int q0 = qhalf * 64 + w * 16;

  bf16x8 aq[2];
  #pragma unroll
  for (int kk = 0; kk < 2; ++kk)
    aq[kk] = *reinterpret_cast<const bf16x8*>(
        qh + (size_t)(b * 128 + q0 + lo) * 512 + h * 64 + kk * 32 + hi * 8);

  float mrow[4], lrow[4];
  #pragma unroll
  for (int i = 0; i < 4; ++i) { mrow[i] = -1e30f; lrow[i] = 0.f; }
  f32x4 o[4] = {};

  const unsigned short* kp = kbuf + (size_t)bh * 4096 * 64;
  const unsigned short* vp = vT + (size_t)bh * 64 * 4096;
  const float* mp = mask + ((size_t)b * 128 + q0) * 4096;

  for (int nt = 0; nt < 64; ++nt) {
    {
      const uint4* src = reinterpret_cast<const uint4*>(kp + (size_t)nt * 4096);
      uint4* dst = reinterpret_cast<uint4*>(Ks);
      const int sw = (t >> 3) & 7;
      dst[t ^ sw] = src[t];
      dst[256 + (t ^ sw)] = src[t + 256];
      const int d0 = t >> 3;
      const int vsw = (((t & 7) ^ (d0 & 7))) * 8;
      *reinterpret_cast<uint4*>(&Vs[d0 * 64 + vsw]) =
          *reinterpret_cast<const uint4*>(vp + (size_t)d0 * 4096 + nt * 64 + (t & 7) * 8);
      *reinterpret_cast<uint4*>(&Vs[(d0 + 32) * 64 + vsw]) =
          *reinterpret_cast<const uint4*>(vp + (size_t)(d0 + 32) * 4096 + nt * 64 + (t & 7) * 8);
    }
    __syncthreads();

    f32x4 s[4] = {};
    #pragma unroll
    for (int ni = 0; ni < 4; ++ni) {
      #pragma unroll
      for (int kk = 0; kk < 2; ++kk) {
        const bf16x8 kf = *reinterpret_cast<const bf16x8*>(
            &Ks[(ni * 16 + lo) * 64 + ((kk * 32 + hi * 8) ^ ((lo & 7) << 3))]);
        s[ni] = mfma16(aq[kk], kf, s[ni]);
      }
    }
    #pragma unroll
    for (int ni = 0; ni < 4; ++ni)
      #pragma unroll
      for (int r = 0; r < 4; ++r)
        s[ni][r] += mp[(size_t)(hi * 4 + r) * 4096 + nt * 64 + ni * 16 + lo];

    #pragma unroll
    for (int r = 0; r < 4; ++r) {
      float mx = fmaxf(fmaxf(s[0][r], s[1][r]), fmaxf(s[2][r], s[3][r]));
      #pragma unroll
      for (int off = 1; off < 16; off <<= 1)
        mx = fmaxf(mx, __shfl_xor(mx, off, 64));
      const float mnew = fmaxf(mrow[r], mx);
      const float corr = __expf(mrow[r] - mnew);
      mrow[r] = mnew;
      float ls = 0.f;
      #pragma unroll
      for (int ni = 0; ni < 4; ++ni) {
        const float p = __expf(s[ni][r] - mnew);
        s[ni][r] = p; ls += p;
      }
      #pragma unroll
      for (int off = 1; off < 16; off <<= 1)
        ls += __shfl_xor(ls, off, 64);
      lrow[r] = lrow[r] * corr + ls;
      #pragma unroll
      for (int di = 0; di < 4; ++di)
        o[di][r] *= corr;
    }

    #pragma unroll
    for (int ni = 0; ni < 4; ++ni)
      #pragma unroll
      for (int r = 0; r < 4; ++r) {
        const int rp = hi * 4 + r;
        Ps[w][rp * 64 + ((ni * 16 + lo) ^ ((rp & 7) << 3))] = f2bf(s[ni][r]);
      }

    #pragma unroll
    for (int kk = 0; kk < 2; ++kk) {
      const bf16x8 pa = *reinterpret_cast<const bf16x8*>(
          &Ps[w][lo * 64 + ((kk * 32 + hi * 8) ^ ((lo & 7) << 3))]);
      #pragma unroll
      for (int di = 0; di < 4; ++di) {
        const bf16x8 vf = *reinterpret_cast<const bf16x8*>(
            &Vs[(di * 16 + lo) * 64 + ((kk * 32 + hi * 8) ^ ((lo & 7) << 3))]);
        o[di] = mfma16(pa, vf, o[di]);
      }
    }
    __syncthreads();
  }

  #pragma unroll
  for (int di = 0; di < 4; ++di)
    #pragma unroll
    for (int r = 0; r < 4; ++r)
      xout[(size_t)(b * 128 + q0 + hi * 4 + r) * 512 + h * 64 + di * 16 + lo] =
          f2bf(o[di][r] / lrow[r]);
}

extern "C" void kernel_launch(void* const* d_in, const int* in_sizes, int n_in,
                              void* d_out, int out_size, void* d_ws, size_t ws_size,
                              hipStream_t stream) {
  const float* q     = (const float*)d_in[0];
  const float* kv    = (const float*)d_in[1];
  const float* mask  = (const float*)d_in[2];
  const float* Wq    = (const float*)d_in[3];
  const float* Wkv   = (const float*)d_in[4];
  const float* Wproj = (const float*)d_in[5];
  const float* bproj = (const float*)d_in[6];
  float* out = (float*)d_out;

  char* ws = (char*)d_ws;
  unsigned short* qhb    = (unsigned short*)ws;                          // 4 MiB
  unsigned short* kvb    = (unsigned short*)(ws + (4ULL << 20));         // 128 MiB (k)
  unsigned short* vTb    = kvb + 67108864ULL;                            // 128 MiB (vT)
  unsigned short* xb     = (unsigned short*)(ws + (260ULL << 20));       // 4 MiB
  unsigned short* Wqb    = (unsigned short*)(ws + (264ULL << 20));       // 0.5 MiB
  unsigned short* Wkvb   = (unsigned short*)(ws + (264ULL << 20) + (512ULL << 10)); // 1 MiB
  unsigned short* Wprojb = (unsigned short*)(ws + (265ULL << 20) + (512ULL << 10)); // 0.5 MiB

  cvt_f32_bf16<<<64, 256, 0, stream>>>(Wq, Wqb, 512 * 512 / 8);
  cvt_f32_bf16<<<128, 256, 0, stream>>>(Wkv, Wkvb, 1024 * 512 / 8);
  cvt_f32_bf16<<<64, 256, 0, stream>>>(Wproj, Wprojb, 512 * 512 / 8);

  // 1) qh = (q @ Wq^T) * scale           M=4096  N=512
  gemm_bt<0, true><<<128, 256, 0, stream>>>(q, Wqb, qhb, nullptr);
  // 2) kvp = kv @ Wkv^T -> k, vT         M=131072 N=1024
  gemm_bt<1, true><<<8192, 256, 0, stream>>>(kv, Wkvb, kvb, nullptr);
  // 3) flash attention -> x bf16
  attn_fwd<<<512, 256, 0, stream>>>(qhb, kvb, vTb, mask, xb);
  // 4) out = x @ Wproj^T + bproj         M=4096  N=512
  gemm_bt<2, false><<<128, 256, 0, stream>>>(xb, Wprojb, out, bproj);
}

// Round 3
// 496.535 us; speedup vs baseline: 1.6053x; 1.2320x over previous
//
#include <hip/hip_runtime.h>
#include <hip/hip_bf16.h>

typedef __attribute__((ext_vector_type(4))) float f32x4;
typedef __attribute__((ext_vector_type(8))) short bf16x8;

#define GAS __attribute__((address_space(1)))
#define LAS __attribute__((address_space(3)))

__device__ __forceinline__ unsigned int cvtpk(float lo, float hi) {
  unsigned int r;
  asm("v_cvt_pk_bf16_f32 %0, %1, %2" : "=v"(r) : "v"(lo), "v"(hi));
  return r;
}
__device__ __forceinline__ unsigned short f2bf(float f) { return (unsigned short)cvtpk(f, f); }
__device__ __forceinline__ f32x4 mfma16(bf16x8 a, bf16x8 b, f32x4 c) {
  return __builtin_amdgcn_mfma_f32_16x16x32_bf16(a, b, c, 0, 0, 0);
}
__device__ __forceinline__ void gl_lds16(const unsigned short* g, unsigned short* l) {
  __builtin_amdgcn_global_load_lds((const GAS unsigned short*)g, (LAS unsigned short*)l, 16, 0, 0);
}
__device__ __forceinline__ void memfence_sched() { asm volatile("" ::: "memory"); }

__global__ __launch_bounds__(256)
void cvt_f32_bf16(const float* __restrict__ in, unsigned short* __restrict__ out, int n8) {
  for (int i = blockIdx.x * blockDim.x + threadIdx.x; i < n8; i += gridDim.x * blockDim.x) {
    const float4 a = *reinterpret_cast<const float4*>(in + (size_t)i * 8);
    const float4 b = *reinterpret_cast<const float4*>(in + (size_t)i * 8 + 4);
    uint4 o;
    o.x = cvtpk(a.x, a.y); o.y = cvtpk(a.z, a.w);
    o.z = cvtpk(b.x, b.y); o.w = cvtpk(b.z, b.w);
    *reinterpret_cast<uint4*>(out + (size_t)i * 8) = o;
  }
}

// C[M,N] = A[M,512] @ B[N,512]^T, A/B bf16. 256x256 tile, BK=32, NK=16.
// 512 threads (8 waves: wm=w>>2, wn=w&3; per-wave 128x64 out).
// 4 LDS K-tile buffers (A 16KB + B 16KB) = 128 KB; gl_lds prefetch 3 ahead;
// counted vmcnt (steady vmcnt(8)); 1 barrier/K-step; setprio around MFMA.
// Swizzle: 16B-chunk ^= (row>>1)&3, pre-swizzled global source.
// MODE 0: bf16 out *0.125 ; MODE 1: bf16 out ; MODE 2: f32 out + bias.
template<int MODE>
__global__ __launch_bounds__(512, 2)
void gemm8(const unsigned short* __restrict__ Ag, const unsigned short* __restrict__ Bg,
           void* __restrict__ Cg, const float* __restrict__ bias, int ntn, int ldc)
{
  __shared__ unsigned short sm[65536];   // A buf k: k*8192 ; B buf k: 32768 + k*8192
  const int t = threadIdx.x, lane = t & 63, w = t >> 6;
  const int lo = lane & 15, hi = lane >> 4;
  const int wm = w >> 2, wn = w & 3;
  const int nwg = gridDim.x, bid = blockIdx.x;
  const int id = (bid & 7) * (nwg >> 3) + (bid >> 3);   // XCD swizzle (nwg%8==0)
  const int row0 = (id / ntn) * 256, col0 = (id % ntn) * 256;
  const int w16 = w * 16;

  const int cxor = (lane >> 3) & 3;                     // ((stage_row)>>1)&3
  const size_t a_src = (size_t)(row0 + w16 + (lane >> 2)) * 512 + (((lane & 3) ^ cxor) << 3);
  const size_t b_src = (size_t)(col0 + w16 + (lane >> 2)) * 512 + (((lane & 3) ^ cxor) << 3);

  auto STAGE_A = [&](int kt) {
    unsigned short* ab = &sm[(kt & 3) * 8192];
    gl_lds16(Ag + a_src + kt * 32, ab + w16 * 32);
    gl_lds16(Ag + a_src + (size_t)128 * 512 + kt * 32, ab + (128 + w16) * 32);
  };
  auto STAGE_B = [&](int kt) {
    unsigned short* bb = &sm[32768 + (kt & 3) * 8192];
    gl_lds16(Bg + b_src + kt * 32, bb + w16 * 32);
    gl_lds16(Bg + b_src + (size_t)128 * 512 + kt * 32, bb + (128 + w16) * 32);
  };

  f32x4 acc[8][4] = {};
  const int fxor = (hi ^ ((lo >> 1) & 3)) << 3;

  auto CONSUME = [&](int kt, bool pf) {
    const unsigned short* ab = &sm[(kt & 3) * 8192];
    const unsigned short* bb = &sm[32768 + (kt & 3) * 8192];
    if (pf) STAGE_A(kt + 3);
    bf16x8 bfr[4], af[4];
    #pragma unroll
    for (int nj = 0; nj < 4; ++nj)
      bfr[nj] = *reinterpret_cast<const bf16x8*>(&bb[(wn * 64 + nj * 16 + lo) * 32 + fxor]);
    #pragma unroll
    for (int mi = 0; mi < 4; ++mi)
      af[mi] = *reinterpret_cast<const bf16x8*>(&ab[(wm * 128 + mi * 16 + lo) * 32 + fxor]);
    __builtin_amdgcn_s_setprio(1);
    #pragma unroll
    for (int mi = 0; mi < 4; ++mi)
      #pragma unroll
      for (int nj = 0; nj < 4; ++nj)
        acc[mi][nj] = mfma16(af[mi], bfr[nj], acc[mi][nj]);
    __builtin_amdgcn_s_setprio(0);
    if (pf) STAGE_B(kt + 3);
    #pragma unroll
    for (int mi = 0; mi < 4; ++mi)
      af[mi] = *reinterpret_cast<const bf16x8*>(&ab[(wm * 128 + (mi + 4) * 16 + lo) * 32 + fxor]);
    __builtin_amdgcn_s_setprio(1);
    #pragma unroll
    for (int mi = 0; mi < 4; ++mi)
      #pragma unroll
      for (int nj = 0; nj < 4; ++nj)
        acc[mi + 4][nj] = mfma16(af[mi], bfr[nj], acc[mi + 4][nj]);
    __builtin_amdgcn_s_setprio(0);
  };

  STAGE_A(0); STAGE_B(0); STAGE_A(1); STAGE_B(1); STAGE_A(2); STAGE_B(2);
  asm volatile("s_waitcnt vmcnt(8)" ::: "memory");
  __builtin_amdgcn_s_barrier();
  memfence_sched();

  for (int kt = 0; kt < 16; ++kt) {
    CONSUME(kt, kt < 13);
    memfence_sched();
    if (kt < 13)       { asm volatile("s_waitcnt vmcnt(8)" ::: "memory"); }
    else if (kt == 13) { asm volatile("s_waitcnt vmcnt(4)" ::: "memory"); }
    else if (kt == 14) { asm volatile("s_waitcnt vmcnt(0)" ::: "memory"); }
    if (kt < 15) { __builtin_amdgcn_s_barrier(); memfence_sched(); }
  }

  #pragma unroll
  for (int mi = 0; mi < 8; ++mi) {
    #pragma unroll
    for (int r = 0; r < 4; ++r) {
      const size_t gm = (size_t)row0 + wm * 128 + mi * 16 + hi * 4 + r;
      #pragma unroll
      for (int nj = 0; nj < 4; ++nj) {
        const int gn = col0 + wn * 64 + nj * 16 + lo;
        const float v = acc[mi][nj][r];
        if constexpr (MODE == 0)
          ((unsigned short*)Cg)[gm * ldc + gn] = f2bf(v * 0.125f);
        else if constexpr (MODE == 1)
          ((unsigned short*)Cg)[gm * (size_t)ldc + gn] = f2bf(v);
        else
          ((float*)Cg)[gm * ldc + gn] = v + bias[gn];
      }
    }
  }
}

// Flash attention: grid = B*H*2 = 512, 256 threads (4 waves x 16 q-rows).
// k layout [b*4096+n, 512] (col = h*64+d); vT layout [2][512][65536].
__global__ __launch_bounds__(256)
void attn_fwd(const unsigned short* __restrict__ qh,
              const unsigned short* __restrict__ kbuf,
              const unsigned short* __restrict__ vT,
              const float* __restrict__ mask,
              unsigned short* __restrict__ xout)
{
  __shared__ unsigned short Ks[64 * 64];
  __shared__ unsigned short Vs[64 * 64];
  __shared__ unsigned short Ps[4][16 * 64];
  const int bh2 = blockIdx.x;
  const int bh = bh2 >> 1, qhalf = bh2 & 1;
  const int b = bh >> 3, h = bh & 7;
  const int t = threadIdx.x, lane = t & 63, w = t >> 6;
  const int hi = lane >> 4, lo = lane & 15;
  const int q0 = qhalf * 64 + w * 16;

  bf16x8 aq[2];
  #pragma unroll
  for (int kk = 0; kk < 2; ++kk)
    aq[kk] = *reinterpret_cast<const bf16x8*>(
        qh + (size_t)(b * 128 + q0 + lo) * 512 + h * 64 + kk * 32 + hi * 8);

  float mrow[4], lrow[4];
  #pragma unroll
  for (int i = 0; i < 4; ++i) { mrow[i] = -1e30f; lrow[i] = 0.f; }
  f32x4 o[4] = {};

  const unsigned short* kp = kbuf + ((size_t)b * 4096) * 512 + h * 64;
  const unsigned short* vp = vT + (size_t)(b >> 4) * (512ULL * 65536) + (size_t)(b & 15) * 4096;
  const float* mp = mask + ((size_t)b * 128 + q0) * 4096;

  for (int nt = 0; nt < 64; ++nt) {
    {
      const int r = t >> 3, c = t & 7;
      *reinterpret_cast<uint4*>(&Ks[r * 64 + ((c ^ (r & 7)) << 3)]) =
          *reinterpret_cast<const uint4*>(kp + (size_t)(nt * 64 + r) * 512 + (c << 3));
      *reinterpret_cast<uint4*>(&Ks[(r + 32) * 64 + ((c ^ (r & 7)) << 3)]) =
          *reinterpret_cast<const uint4*>(kp + (size_t)(nt * 64 + r + 32) * 512 + (c << 3));
      *reinterpret_cast<uint4*>(&Vs[r * 64 + ((c ^ (r & 7)) << 3)]) =
          *reinterpret_cast<const uint4*>(vp + (size_t)(h * 64 + r) * 65536 + nt * 64 + (c << 3));
      *reinterpret_cast<uint4*>(&Vs[(r + 32) * 64 + ((c ^ (r & 7)) << 3)]) =
          *reinterpret_cast<const uint4*>(vp + (size_t)(h * 64 + r + 32) * 65536 + nt * 64 + (c << 3));
    }
    __syncthreads();

    f32x4 s[4] = {};
    __builtin_amdgcn_s_setprio(1);
    #pragma unroll
    for (int ni = 0; ni < 4; ++ni) {
      #pragma unroll
      for (int kk = 0; kk < 2; ++kk) {
        const bf16x8 kf = *reinterpret_cast<const bf16x8*>(
            &Ks[(ni * 16 + lo) * 64 + ((kk * 32 + hi * 8) ^ ((lo & 7) << 3))]);
        s[ni] = mfma16(aq[kk], kf, s[ni]);
      }
    }
    __builtin_amdgcn_s_setprio(0);
    #pragma unroll
    for (int ni = 0; ni < 4; ++ni)
      #pragma unroll
      for (int r = 0; r < 4; ++r)
        s[ni][r] += mp[(size_t)(hi * 4 + r) * 4096 + nt * 64 + ni * 16 + lo];

    #pragma unroll
    for (int r = 0; r < 4; ++r) {
      float mx = fmaxf(fmaxf(s[0][r], s[1][r]), fmaxf(s[2][r], s[3][r]));
      #pragma unroll
      for (int off = 1; off < 16; off <<= 1)
        mx = fmaxf(mx, __shfl_xor(mx, off, 64));
      const float mnew = fmaxf(mrow[r], mx);
      const float corr = __expf(mrow[r] - mnew);
      mrow[r] = mnew;
      float ls = 0.f;
      #pragma unroll
      for (int ni = 0; ni < 4; ++ni) {
        const float p = __expf(s[ni][r] - mnew);
        s[ni][r] = p; ls += p;
      }
      #pragma unroll
      for (int off = 1; off < 16; off <<= 1)
        ls += __shfl_xor(ls, off, 64);
      lrow[r] = lrow[r] * corr + ls;
      #pragma unroll
      for (int di = 0; di < 4; ++di)
        o[di][r] *= corr;
    }

    #pragma unroll
    for (int ni = 0; ni < 4; ++ni)
      #pragma unroll
      for (int r = 0; r < 4; ++r) {
        const int rp = hi * 4 + r;
        Ps[w][rp * 64 + ((ni * 16 + lo) ^ ((rp & 7) << 3))] = f2bf(s[ni][r]);
      }

    __builtin_amdgcn_s_setprio(1);
    #pragma unroll
    for (int kk = 0; kk < 2; ++kk) {
      const bf16x8 pa = *reinterpret_cast<const bf16x8*>(
          &Ps[w][lo * 64 + ((kk * 32 + hi * 8) ^ ((lo & 7) << 3))]);
      #pragma unroll
      for (int di = 0; di < 4; ++di) {
        const bf16x8 vf = *reinterpret_cast<const bf16x8*>(
            &Vs[(di * 16 + lo) * 64 + ((kk * 32 + hi * 8) ^ ((lo & 7) << 3))]);
        o[di] = mfma16(pa, vf, o[di]);
      }
    }
    __builtin_amdgcn_s_setprio(0);
    __syncthreads();
  }

  #pragma unroll
  for (int di = 0; di < 4; ++di)
    #pragma unroll
    for (int r = 0; r < 4; ++r)
      xout[(size_t)(b * 128 + q0 + hi * 4 + r) * 512 + h * 64 + di * 16 + lo] =
          f2bf(o[di][r] / lrow[r]);
}

extern "C" void kernel_launch(void* const* d_in, const int* in_sizes, int n_in,
                              void* d_out, int out_size, void* d_ws, size_t ws_size,
                              hipStream_t stream) {
  const float* q     = (const float*)d_in[0];
  const float* kv    = (const float*)d_in[1];
  const float* mask  = (const float*)d_in[2];
  const float* Wq    = (const float*)d_in[3];
  const float* Wkv   = (const float*)d_in[4];
  const float* Wproj = (const float*)d_in[5];
  const float* bproj = (const float*)d_in[6];
  float* out = (float*)d_out;

  char* ws = (char*)d_ws;
  unsigned short* kbuf   = (unsigned short*)ws;                      // 134.2 MB [131072,512]
  unsigned short* vTb    = (unsigned short*)(ws + 134217728ULL);     // 134.2 MB [2][512][65536]
  unsigned short* kvbfc  = (unsigned short*)(ws + 268435456ULL);     // 67.1 MB rotating chunk
  unsigned short* qbf    = kvbfc;                                    // 4.2 MB (before kv chunks)
  unsigned short* xb     = kvbfc;                                    // 4.2 MB (after kv chunks)
  unsigned short* qhb    = (unsigned short*)(ws + 335544320ULL);     // 4.2 MB
  unsigned short* Wqb    = (unsigned short*)(ws + 339738624ULL);     // 0.5 MB
  unsigned short* Wkvb   = (unsigned short*)(ws + 340262912ULL);     // 1.0 MB
  unsigned short* Wprojb = (unsigned short*)(ws + 341311488ULL);     // 0.5 MB

  cvt_f32_bf16<<<128, 256, 0, stream>>>(Wq, Wqb, 512 * 512 / 8);
  cvt_f32_bf16<<<256, 256, 0, stream>>>(Wkv, Wkvb, 1024 * 512 / 8);
  cvt_f32_bf16<<<128, 256, 0, stream>>>(Wproj, Wprojb, 512 * 512 / 8);

  // qh = (q @ Wq^T) * scale   (qbf aliases kvbfc; used before kv chunks)
  cvt_f32_bf16<<<512, 256, 0, stream>>>(q, qbf, 4096 * 512 / 8);
  gemm8<0><<<32, 512, 0, stream>>>(qbf, Wqb, qhb, nullptr, 2, 512);

  for (int c = 0; c < 2; ++c) {
    cvt_f32_bf16<<<2048, 256, 0, stream>>>(kv + (size_t)c * 65536 * 512, kvbfc, 65536 * 512 / 8);
    // k chunk: [65536,512] @ Wk^T -> kbuf rows
    gemm8<1><<<512, 512, 0, stream>>>(kvbfc, Wkvb, kbuf + (size_t)c * 65536 * 512,
                                      nullptr, 2, 512);
    // v chunk: Wv @ kv^T -> vT chunk [512, 65536]
    gemm8<1><<<512, 512, 0, stream>>>(Wkvb + 512 * 512, kvbfc, vTb + (size_t)c * 512 * 65536,
                                      nullptr, 256, 65536);
  }

  // flash attention -> xb bf16 (aliases kvbfc; kv chunks fully consumed)
  attn_fwd<<<512, 256, 0, stream>>>(qhb, kbuf, vTb, mask, xb);

  // out = x @ Wproj^T + bproj
  gemm8<2><<<32, 512, 0, stream>>>(xb, Wprojb, out, bproj, 2, 512);
}

// Round 4
// 449.206 us; speedup vs baseline: 1.7744x; 1.1054x over previous
//
#include <hip/hip_runtime.h>
#include <hip/hip_bf16.h>

typedef __attribute__((ext_vector_type(4))) float f32x4;
typedef __attribute__((ext_vector_type(8))) short bf16x8;

#define GAS __attribute__((address_space(1)))
#define LAS __attribute__((address_space(3)))

__device__ __forceinline__ unsigned int cvtpk(float lo, float hi) {
  unsigned int r;
  asm("v_cvt_pk_bf16_f32 %0, %1, %2" : "=v"(r) : "v"(lo), "v"(hi));
  return r;
}
__device__ __forceinline__ unsigned short f2bf(float f) { return (unsigned short)cvtpk(f, f); }
__device__ __forceinline__ f32x4 mfma16(bf16x8 a, bf16x8 b, f32x4 c) {
  return __builtin_amdgcn_mfma_f32_16x16x32_bf16(a, b, c, 0, 0, 0);
}
__device__ __forceinline__ void gl_lds16(const unsigned short* g, unsigned short* l) {
  __builtin_amdgcn_global_load_lds((const GAS unsigned short*)g, (LAS unsigned short*)l, 16, 0, 0);
}
__device__ __forceinline__ void memfence_sched() { asm volatile("" ::: "memory"); }

__global__ __launch_bounds__(256)
void cvt_f32_bf16(const float* __restrict__ in, unsigned short* __restrict__ out, int n8) {
  for (int i = blockIdx.x * blockDim.x + threadIdx.x; i < n8; i += gridDim.x * blockDim.x) {
    const float4 a = *reinterpret_cast<const float4*>(in + (size_t)i * 8);
    const float4 b = *reinterpret_cast<const float4*>(in + (size_t)i * 8 + 4);
    uint4 o;
    o.x = cvtpk(a.x, a.y); o.y = cvtpk(a.z, a.w);
    o.z = cvtpk(b.x, b.y); o.w = cvtpk(b.z, b.w);
    *reinterpret_cast<uint4*>(out + (size_t)i * 8) = o;
  }
}

// C[M,N] = A[M,512] @ B[N,512]^T. Operand paths: F32 -> fp32 reg-staged +
// cvt_pk -> swizzled ds_write (2 LDS slots, 2 reg banks); else bf16 via
// global_load_lds (3 LDS slots, pre-swizzled source). BK=32, 16 K-steps,
// prefetch depth 2, steady s_waitcnt vmcnt(6) (mixed) / vmcnt(4) (pure-gl).
// 256x256 tile, 512 thr (8 waves 2x4), per-wave 128x64.
// MODE 0: bf16 *0.125 ; MODE 1: bf16 ; MODE 2: f32 + bias.
template<int MODE, bool AF32, bool BF32>
__global__ __launch_bounds__(512, 2)
void gemm8(const void* __restrict__ Agv, const void* __restrict__ Bgv,
           void* __restrict__ Cg, const float* __restrict__ bias, int ntn, size_t ldc)
{
  constexpr int NA = AF32 ? 2 : 3;
  constexpr int NB = BF32 ? 2 : 3;
  constexpr int SOPS = (AF32 || BF32) ? 6 : 4;   // vm ops per stage (A+B)
  __shared__ unsigned short sm[(NA + NB) * 8192];
  unsigned short* const smB = sm + NA * 8192;

  const int t = threadIdx.x, lane = t & 63, w = t >> 6;
  const int lo = lane & 15, hi = lane >> 4;
  const int wm = w >> 2, wn = w & 3;
  const int nwg = gridDim.x, bid = blockIdx.x;
  const int id = (bid & 7) * (nwg >> 3) + (bid >> 3);   // XCD swizzle (nwg%8==0)
  const int row0 = (id / ntn) * 256, col0 = (id % ntn) * 256;
  const int w16 = w * 16;

  const unsigned short* Ab = (const unsigned short*)Agv;
  const unsigned short* Bb = (const unsigned short*)Bgv;
  const float* Af = (const float*)Agv;
  const float* Bf = (const float*)Bgv;

  // gl_lds path addressing (pre-swizzled source)
  const int cxor_g = (lane >> 3) & 3;
  const size_t a_src_g = (size_t)(row0 + w16 + (lane >> 2)) * 512 + (((lane & 3) ^ cxor_g) << 3);
  const size_t b_src_g = (size_t)(col0 + w16 + (lane >> 2)) * 512 + (((lane & 3) ^ cxor_g) << 3);

  // f32 reg-staged addressing
  const int rs_r = t >> 2;                 // row within 128-row half
  const int rs_c = (t & 3) * 8;            // col within 32
  const int wch = ((t & 3) ^ ((t >> 3) & 3)) << 3;   // swizzled ush offset in row

  float4 stA[2][4];                        // [bank][piece]
  float4 stB[2][4];

  auto A_ISSUE = [&](int kt, int bank) {
    if constexpr (AF32) {
      const float* s0 = Af + (size_t)(row0 + rs_r) * 512 + kt * 32 + rs_c;
      const float* s1 = Af + (size_t)(row0 + 128 + rs_r) * 512 + kt * 32 + rs_c;
      stA[bank][0] = *(const float4*)s0; stA[bank][1] = *(const float4*)(s0 + 4);
      stA[bank][2] = *(const float4*)s1; stA[bank][3] = *(const float4*)(s1 + 4);
    } else {
      unsigned short* ab = &sm[(kt % NA) * 8192];
      gl_lds16(Ab + a_src_g + kt * 32, ab + w16 * 32);
      gl_lds16(Ab + a_src_g + (size_t)128 * 512 + kt * 32, ab + (128 + w16) * 32);
    }
  };
  auto B_ISSUE = [&](int kt, int bank) {
    if constexpr (BF32) {
      const float* s0 = Bf + (size_t)(col0 + rs_r) * 512 + kt * 32 + rs_c;
      const float* s1 = Bf + (size_t)(col0 + 128 + rs_r) * 512 + kt * 32 + rs_c;
      stB[bank][0] = *(const float4*)s0; stB[bank][1] = *(const float4*)(s0 + 4);
      stB[bank][2] = *(const float4*)s1; stB[bank][3] = *(const float4*)(s1 + 4);
    } else {
      unsigned short* bb = &smB[(kt % NB) * 8192];
      gl_lds16(Bb + b_src_g + kt * 32, bb + w16 * 32);
      gl_lds16(Bb + b_src_g + (size_t)128 * 512 + kt * 32, bb + (128 + w16) * 32);
    }
  };
  auto A_WRITE = [&](int kt, int bank) {
    if constexpr (AF32) {
      unsigned short* ab = &sm[(kt % NA) * 8192];
      uint4 o;
      o.x = cvtpk(stA[bank][0].x, stA[bank][0].y); o.y = cvtpk(stA[bank][0].z, stA[bank][0].w);
      o.z = cvtpk(stA[bank][1].x, stA[bank][1].y); o.w = cvtpk(stA[bank][1].z, stA[bank][1].w);
      *reinterpret_cast<uint4*>(&ab[rs_r * 32 + wch]) = o;
      o.x = cvtpk(stA[bank][2].x, stA[bank][2].y); o.y = cvtpk(stA[bank][2].z, stA[bank][2].w);
      o.z = cvtpk(stA[bank][3].x, stA[bank][3].y); o.w = cvtpk(stA[bank][3].z, stA[bank][3].w);
      *reinterpret_cast<uint4*>(&ab[(128 + rs_r) * 32 + wch]) = o;
    }
  };
  auto B_WRITE = [&](int kt, int bank) {
    if constexpr (BF32) {
      unsigned short* bb = &smB[(kt % NB) * 8192];
      uint4 o;
      o.x = cvtpk(stB[bank][0].x, stB[bank][0].y); o.y = cvtpk(stB[bank][0].z, stB[bank][0].w);
      o.z = cvtpk(stB[bank][1].x, stB[bank][1].y); o.w = cvtpk(stB[bank][1].z, stB[bank][1].w);
      *reinterpret_cast<uint4*>(&bb[rs_r * 32 + wch]) = o;
      o.x = cvtpk(stB[bank][2].x, stB[bank][2].y); o.y = cvtpk(stB[bank][2].z, stB[bank][2].w);
      o.z = cvtpk(stB[bank][3].x, stB[bank][3].y); o.w = cvtpk(stB[bank][3].z, stB[bank][3].w);
      *reinterpret_cast<uint4*>(&bb[(128 + rs_r) * 32 + wch]) = o;
    }
  };

  f32x4 acc[8][4] = {};
  const int fxor = (hi ^ ((lo >> 1) & 3)) << 3;

  // prologue: stage tiles 0,1
  A_ISSUE(0, 0); B_ISSUE(0, 0);
  A_ISSUE(1, 1); B_ISSUE(1, 1);
  memfence_sched();
  if constexpr (SOPS == 6) asm volatile("s_waitcnt vmcnt(6)" ::: "memory");
  else                     asm volatile("s_waitcnt vmcnt(4)" ::: "memory");
  A_WRITE(0, 0); B_WRITE(0, 0);
  asm volatile("s_waitcnt lgkmcnt(0)" ::: "memory");
  __builtin_amdgcn_s_barrier();
  memfence_sched();

  #pragma unroll
  for (int kt = 0; kt < 16; ++kt) {
    const unsigned short* ab = &sm[(kt % NA) * 8192];
    const unsigned short* bb = &smB[(kt % NB) * 8192];
    bf16x8 bfr[4], af[4];
    #pragma unroll
    for (int nj = 0; nj < 4; ++nj)
      bfr[nj] = *reinterpret_cast<const bf16x8*>(&bb[(wn * 64 + nj * 16 + lo) * 32 + fxor]);
    #pragma unroll
    for (int mi = 0; mi < 4; ++mi)
      af[mi] = *reinterpret_cast<const bf16x8*>(&ab[(wm * 128 + mi * 16 + lo) * 32 + fxor]);
    if (kt + 2 <= 15) { A_ISSUE(kt + 2, kt & 1); B_ISSUE(kt + 2, kt & 1); }
    memfence_sched();
    __builtin_amdgcn_s_setprio(1);
    #pragma unroll
    for (int mi = 0; mi < 4; ++mi)
      #pragma unroll
      for (int nj = 0; nj < 4; ++nj)
        acc[mi][nj] = mfma16(af[mi], bfr[nj], acc[mi][nj]);
    __builtin_amdgcn_s_setprio(0);
    #pragma unroll
    for (int mi = 0; mi < 4; ++mi)
      af[mi] = *reinterpret_cast<const bf16x8*>(&ab[(wm * 128 + (mi + 4) * 16 + lo) * 32 + fxor]);
    if (kt <= 14) {
      if (kt + 2 <= 15) {
        if constexpr (SOPS == 6) asm volatile("s_waitcnt vmcnt(6)" ::: "memory");
        else                     asm volatile("s_waitcnt vmcnt(4)" ::: "memory");
      } else {
        asm volatile("s_waitcnt vmcnt(0)" ::: "memory");
      }
      A_WRITE(kt + 1, (kt + 1) & 1); B_WRITE(kt + 1, (kt + 1) & 1);
    }
    __builtin_amdgcn_s_setprio(1);
    #pragma unroll
    for (int mi = 0; mi < 4; ++mi)
      #pragma unroll
      for (int nj = 0; nj < 4; ++nj)
        acc[mi + 4][nj] = mfma16(af[mi], bfr[nj], acc[mi + 4][nj]);
    __builtin_amdgcn_s_setprio(0);
    if (kt < 15) {
      asm volatile("s_waitcnt lgkmcnt(0)" ::: "memory");
      __builtin_amdgcn_s_barrier();
      memfence_sched();
    }
  }

  #pragma unroll
  for (int mi = 0; mi < 8; ++mi) {
    #pragma unroll
    for (int r = 0; r < 4; ++r) {
      const size_t gm = (size_t)row0 + wm * 128 + mi * 16 + hi * 4 + r;
      #pragma unroll
      for (int nj = 0; nj < 4; ++nj) {
        const int gn = col0 + wn * 64 + nj * 16 + lo;
        const float v = acc[mi][nj][r];
        if constexpr (MODE == 0)
          ((unsigned short*)Cg)[gm * ldc + gn] = f2bf(v * 0.125f);
        else if constexpr (MODE == 1)
          ((unsigned short*)Cg)[gm * ldc + gn] = f2bf(v);
        else
          ((float*)Cg)[gm * ldc + gn] = v + bias[gn];
      }
    }
  }
}

// Flash attention, KV split 4-way: grid = 2048 (b,h,qhalf,chunk), 256 thr
// (4 waves x 16 q-rows). Writes partials (o fp32, m, l) for combine pass.
// k [131072, 512] bf16 (col h*64+d); vT [512, 131072] bf16.
__global__ __launch_bounds__(256)
void attn_fwd(const unsigned short* __restrict__ qh,
              const unsigned short* __restrict__ kbuf,
              const unsigned short* __restrict__ vT,
              const float* __restrict__ mask,
              float* __restrict__ opart, float* __restrict__ ml)
{
  __shared__ unsigned short Ks[64 * 64];
  __shared__ unsigned short Vs[64 * 64];
  __shared__ unsigned short Ps[4][16 * 64];
  const int bid = blockIdx.x;
  const int xcd = bid & 7, g = bid >> 3;
  const int b = (g >> 6) * 8 + xcd;           // blocks sharing b land on one XCD
  const int sub = g & 63;
  const int h = sub >> 3, qhalf = (sub >> 2) & 1, c = sub & 3;
  const int n0 = c * 1024;
  const int bh2 = (b * 8 + h) * 2 + qhalf;
  const int t = threadIdx.x, lane = t & 63, w = t >> 6;
  const int hi = lane >> 4, lo = lane & 15;
  const int q0 = qhalf * 64 + w * 16;

  bf16x8 aq[2];
  #pragma unroll
  for (int kk = 0; kk < 2; ++kk)
    aq[kk] = *reinterpret_cast<const bf16x8*>(
        qh + (size_t)(b * 128 + q0 + lo) * 512 + h * 64 + kk * 32 + hi * 8);

  float mrow[4], lrow[4];
  #pragma unroll
  for (int i = 0; i < 4; ++i) { mrow[i] = -1e30f; lrow[i] = 0.f; }
  f32x4 o[4] = {};

  const unsigned short* kp = kbuf + ((size_t)b * 4096 + n0) * 512 + h * 64;
  const unsigned short* vp = vT + (size_t)(h * 64) * 131072 + (size_t)b * 4096 + n0;
  const float* mp = mask + ((size_t)(b * 128 + q0)) * 4096 + n0;

  for (int nt = 0; nt < 16; ++nt) {
    {
      const int r = t >> 3, cc = t & 7;
      *reinterpret_cast<uint4*>(&Ks[r * 64 + ((cc ^ (r & 7)) << 3)]) =
          *reinterpret_cast<const uint4*>(kp + (size_t)(nt * 64 + r) * 512 + (cc << 3));
      *reinterpret_cast<uint4*>(&Ks[(r + 32) * 64 + ((cc ^ (r & 7)) << 3)]) =
          *reinterpret_cast<const uint4*>(kp + (size_t)(nt * 64 + r + 32) * 512 + (cc << 3));
      *reinterpret_cast<uint4*>(&Vs[r * 64 + ((cc ^ (r & 7)) << 3)]) =
          *reinterpret_cast<const uint4*>(vp + (size_t)r * 131072 + nt * 64 + (cc << 3));
      *reinterpret_cast<uint4*>(&Vs[(r + 32) * 64 + ((cc ^ (r & 7)) << 3)]) =
          *reinterpret_cast<const uint4*>(vp + (size_t)(r + 32) * 131072 + nt * 64 + (cc << 3));
    }
    __syncthreads();

    f32x4 s[4] = {};
    __builtin_amdgcn_s_setprio(1);
    #pragma unroll
    for (int ni = 0; ni < 4; ++ni) {
      #pragma unroll
      for (int kk = 0; kk < 2; ++kk) {
        const bf16x8 kf = *reinterpret_cast<const bf16x8*>(
            &Ks[(ni * 16 + lo) * 64 + ((kk * 32 + hi * 8) ^ ((lo & 7) << 3))]);
        s[ni] = mfma16(aq[kk], kf, s[ni]);
      }
    }
    __builtin_amdgcn_s_setprio(0);
    #pragma unroll
    for (int ni = 0; ni < 4; ++ni)
      #pragma unroll
      for (int r = 0; r < 4; ++r)
        s[ni][r] += mp[(size_t)(hi * 4 + r) * 4096 + nt * 64 + ni * 16 + lo];

    #pragma unroll
    for (int r = 0; r < 4; ++r) {
      float mx = fmaxf(fmaxf(s[0][r], s[1][r]), fmaxf(s[2][r], s[3][r]));
      #pragma unroll
      for (int off = 1; off < 16; off <<= 1)
        mx = fmaxf(mx, __shfl_xor(mx, off, 64));
      const float mnew = fmaxf(mrow[r], mx);
      const float corr = __expf(mrow[r] - mnew);
      mrow[r] = mnew;
      float ls = 0.f;
      #pragma unroll
      for (int ni = 0; ni < 4; ++ni) {
        const float p = __expf(s[ni][r] - mnew);
        s[ni][r] = p; ls += p;
      }
      #pragma unroll
      for (int off = 1; off < 16; off <<= 1)
        ls += __shfl_xor(ls, off, 64);
      lrow[r] = lrow[r] * corr + ls;
      #pragma unroll
      for (int di = 0; di < 4; ++di)
        o[di][r] *= corr;
    }

    #pragma unroll
    for (int ni = 0; ni < 4; ++ni)
      #pragma unroll
      for (int r = 0; r < 4; ++r) {
        const int rp = hi * 4 + r;
        Ps[w][rp * 64 + ((ni * 16 + lo) ^ ((rp & 7) << 3))] = f2bf(s[ni][r]);
      }

    __builtin_amdgcn_s_setprio(1);
    #pragma unroll
    for (int kk = 0; kk < 2; ++kk) {
      const bf16x8 pa = *reinterpret_cast<const bf16x8*>(
          &Ps[w][lo * 64 + ((kk * 32 + hi * 8) ^ ((lo & 7) << 3))]);
      #pragma unroll
      for (int di = 0; di < 4; ++di) {
        const bf16x8 vf = *reinterpret_cast<const bf16x8*>(
            &Vs[(di * 16 + lo) * 64 + ((kk * 32 + hi * 8) ^ ((lo & 7) << 3))]);
        o[di] = mfma16(pa, vf, o[di]);
      }
    }
    __builtin_amdgcn_s_setprio(0);
    __syncthreads();
  }

  // store partials (no division)
  const size_t pbase = ((size_t)bh2 * 4 + c) * 64;
  #pragma unroll
  for (int di = 0; di < 4; ++di)
    #pragma unroll
    for (int r = 0; r < 4; ++r)
      opart[(pbase + (w * 16 + hi * 4 + r)) * 64 + di * 16 + lo] = o[di][r];
  if (lo == 0) {
    #pragma unroll
    for (int r = 0; r < 4; ++r) {
      const int qq = w * 16 + hi * 4 + r;
      ml[(((size_t)bh2 * 4 + c) * 2 + 0) * 64 + qq] = mrow[r];
      ml[(((size_t)bh2 * 4 + c) * 2 + 1) * 64 + qq] = lrow[r];
    }
  }
}

// Combine 4 chunk-partials -> xb bf16. grid = 512 (bh2), 256 thr.
__global__ __launch_bounds__(256)
void attn_combine(const float* __restrict__ opart, const float* __restrict__ ml,
                  unsigned short* __restrict__ xb)
{
  const int bh2 = blockIdx.x;
  const int b = bh2 >> 4, h = (bh2 >> 1) & 7, qhalf = bh2 & 1;
  const int t = threadIdx.x;
  const int q = t >> 2, dg = t & 3;

  float m[4], l[4];
  #pragma unroll
  for (int c = 0; c < 4; ++c) {
    m[c] = ml[(((size_t)bh2 * 4 + c) * 2 + 0) * 64 + q];
    l[c] = ml[(((size_t)bh2 * 4 + c) * 2 + 1) * 64 + q];
  }
  const float M = fmaxf(fmaxf(m[0], m[1]), fmaxf(m[2], m[3]));
  float sc[4], L = 0.f;
  #pragma unroll
  for (int c = 0; c < 4; ++c) { sc[c] = __expf(m[c] - M); L += sc[c] * l[c]; }
  const float inv = 1.f / L;

  float4 acc[4] = {};
  #pragma unroll
  for (int c = 0; c < 4; ++c) {
    const float* base = opart + (((size_t)bh2 * 4 + c) * 64 + q) * 64 + dg * 16;
    #pragma unroll
    for (int j = 0; j < 4; ++j) {
      const float4 v = *reinterpret_cast<const float4*>(base + j * 4);
      acc[j].x = fmaf(sc[c], v.x, acc[j].x);
      acc[j].y = fmaf(sc[c], v.y, acc[j].y);
      acc[j].z = fmaf(sc[c], v.z, acc[j].z);
      acc[j].w = fmaf(sc[c], v.w, acc[j].w);
    }
  }
  unsigned short* dst = xb + ((size_t)b * 128 + qhalf * 64 + q) * 512 + h * 64 + dg * 16;
  uint4 o1, o2;
  o1.x = cvtpk(acc[0].x * inv, acc[0].y * inv); o1.y = cvtpk(acc[0].z * inv, acc[0].w * inv);
  o1.z = cvtpk(acc[1].x * inv, acc[1].y * inv); o1.w = cvtpk(acc[1].z * inv, acc[1].w * inv);
  o2.x = cvtpk(acc[2].x * inv, acc[2].y * inv); o2.y = cvtpk(acc[2].z * inv, acc[2].w * inv);
  o2.z = cvtpk(acc[3].x * inv, acc[3].y * inv); o2.w = cvtpk(acc[3].z * inv, acc[3].w * inv);
  *reinterpret_cast<uint4*>(dst) = o1;
  *reinterpret_cast<uint4*>(dst + 8) = o2;
}

extern "C" void kernel_launch(void* const* d_in, const int* in_sizes, int n_in,
                              void* d_out, int out_size, void* d_ws, size_t ws_size,
                              hipStream_t stream) {
  const float* q     = (const float*)d_in[0];
  const float* kv    = (const float*)d_in[1];
  const float* mask  = (const float*)d_in[2];
  const float* Wq    = (const float*)d_in[3];
  const float* Wkv   = (const float*)d_in[4];
  const float* Wproj = (const float*)d_in[5];
  const float* bproj = (const float*)d_in[6];
  float* out = (float*)d_out;

  char* ws = (char*)d_ws;
  unsigned short* kbuf   = (unsigned short*)ws;                      // 134.2 MB [131072,512]
  unsigned short* vTb    = (unsigned short*)(ws + 134217728ULL);     // 134.2 MB [512,131072]
  float*          opart  = (float*)(ws + 268435456ULL);              // 33.6 MB [512][4][64][64]
  float*          mlb    = (float*)(ws + 301989888ULL);              // 1.0 MB  [512][4][2][64]
  unsigned short* qhb    = (unsigned short*)(ws + 303038464ULL);     // 4.2 MB
  unsigned short* xb     = (unsigned short*)(ws + 307232768ULL);     // 4.2 MB
  unsigned short* Wqb    = (unsigned short*)(ws + 311427072ULL);     // 0.5 MB
  unsigned short* Wkvb   = (unsigned short*)(ws + 311951360ULL);     // 1.0 MB
  unsigned short* Wprojb = (unsigned short*)(ws + 312999936ULL);     // 0.5 MB

  cvt_f32_bf16<<<128, 256, 0, stream>>>(Wq, Wqb, 512 * 512 / 8);
  cvt_f32_bf16<<<256, 256, 0, stream>>>(Wkv, Wkvb, 1024 * 512 / 8);
  cvt_f32_bf16<<<128, 256, 0, stream>>>(Wproj, Wprojb, 512 * 512 / 8);

  // qh = (q @ Wq^T) * scale        M=4096, N=512   (A fp32 fused cvt)
  gemm8<0, true, false><<<32, 512, 0, stream>>>(q, Wqb, qhb, nullptr, 2, 512);
  // k  = kv @ Wk^T                 M=131072, N=512 (A fp32 fused cvt)
  gemm8<1, true, false><<<1024, 512, 0, stream>>>(kv, Wkvb, kbuf, nullptr, 2, 512);
  // vT = Wv @ kv^T                 M=512, N=131072 (B fp32 fused cvt)
  gemm8<1, false, true><<<1024, 512, 0, stream>>>(Wkvb + 512 * 512, kv, vTb, nullptr, 512, 131072);
  // flash attention partials
  attn_fwd<<<2048, 256, 0, stream>>>(qhb, kbuf, vTb, mask, opart, mlb);
  // combine -> xb bf16
  attn_combine<<<512, 256, 0, stream>>>(opart, mlb, xb);
  // out = x @ Wproj^T + bproj
  gemm8<2, false, false><<<32, 512, 0, stream>>>(xb, Wprojb, out, bproj, 2, 512);
}